// Round 8
// baseline (803.956 us; speedup 1.0000x reference)
//
#include <hip/hip_runtime.h>

#define D 128
#define CHUNK 512
#define NSLICE 8
#define SLW 16            // cols per slice

using short8 = __attribute__((ext_vector_type(8))) short;
using f32x4  = __attribute__((ext_vector_type(4))) float;
using f32x2  = __attribute__((ext_vector_type(2))) float;

__device__ __forceinline__ unsigned short f2bf(float f){
  unsigned u = __builtin_bit_cast(unsigned, f);
  u += 0x7fffu + ((u >> 16) & 1u);           // round-to-nearest-even
  return (unsigned short)(u >> 16);
}
__device__ __forceinline__ float bflo2f(unsigned v){
  return __builtin_bit_cast(float, v << 16);
}
__device__ __forceinline__ float bfhi2f(unsigned v){
  return __builtin_bit_cast(float, v & 0xffff0000u);
}
__device__ __forceinline__ float bfs2f(unsigned short v){
  return __builtin_bit_cast(float, ((unsigned)v) << 16);
}
// packed f32x2 -> 2xbf16 in one instruction (gfx950)
__device__ __forceinline__ unsigned cvtpk(float lo, float hi){
  unsigned r;
  asm("v_cvt_pk_bf16_f32 %0, %1, %2" : "=v"(r) : "v"(lo), "v"(hi));
  return r;
}

// ---------------- degree ----------------
__global__ void k_deg(const int* __restrict__ dst, int* __restrict__ deg, int E){
  int e = blockIdx.x * 256 + threadIdx.x;
  if (e < E) atomicAdd(&deg[dst[e]], 1);
}

// ---------------- scan (3-stage) ----------------
__global__ void k_chunksum(const int* __restrict__ deg, int* __restrict__ csum, int n){
  __shared__ int s[256];
  int tid = threadIdx.x;
  int n0 = blockIdx.x * CHUNK + tid * 2;
  int v = 0;
  if (n0     < n) v += deg[n0];
  if (n0 + 1 < n) v += deg[n0 + 1];
  s[tid] = v; __syncthreads();
  for (int off = 128; off > 0; off >>= 1){
    if (tid < off) s[tid] += s[tid + off];
    __syncthreads();
  }
  if (tid == 0) csum[blockIdx.x] = s[0];
}

__global__ void k_scanchunks(int* __restrict__ csum, int nchunks){
  __shared__ int s[256];
  int tid = threadIdx.x;
  int v = (tid < nchunks) ? csum[tid] : 0;
  s[tid] = v; __syncthreads();
  for (int off = 1; off < 256; off <<= 1){
    int t = (tid >= off) ? s[tid - off] : 0;
    __syncthreads();
    s[tid] += t;
    __syncthreads();
  }
  if (tid < nchunks) csum[tid] = s[tid] - v;   // exclusive
}

__global__ void k_offsets(const int* __restrict__ deg, const int* __restrict__ csum,
                          int* __restrict__ offs, float* __restrict__ inv, int n){
  __shared__ int s[256];
  int tid = threadIdx.x;
  int n0 = blockIdx.x * CHUNK + tid * 2;
  int d0 = (n0     < n) ? deg[n0]     : 0;
  int d1 = (n0 + 1 < n) ? deg[n0 + 1] : 0;
  int pair = d0 + d1;
  s[tid] = pair; __syncthreads();
  for (int off = 1; off < 256; off <<= 1){
    int t = (tid >= off) ? s[tid - off] : 0;
    __syncthreads();
    s[tid] += t;
    __syncthreads();
  }
  int excl = s[tid] - pair + csum[blockIdx.x];
  if (n0     <= n) offs[n0]     = excl;
  if (n0 + 1 <= n) offs[n0 + 1] = excl + d0;
  if (n0     < n) inv[n0]     = rsqrtf((float)(d0 + 1));
  if (n0 + 1 < n) inv[n0 + 1] = rsqrtf((float)(d1 + 1));
}

// ---------------- CSR fill (index only — weight folded into hw rows) ------
__global__ void k_csrfill(const int* __restrict__ src, const int* __restrict__ dst,
                          const int* __restrict__ offs, int* __restrict__ cursor,
                          int* __restrict__ csrc, int E){
  int e = blockIdx.x * 256 + threadIdx.x;
  if (e >= E) return;
  int s = src[e], d = dst[e];
  int pos = offs[d] + atomicAdd(&cursor[d], 1);
  csrc[pos] = s;
}

// ---------------- GEMM: hwS(bf16, slice-major) = act(hin) @ W, rows × inv --
// hwS layout: [slice][N][16] ushorts. agg input (do_norm) also slice-major.
#define WSTRIDE 136
__global__ __launch_bounds__(512)
void k_gemm(const float* __restrict__ hf, const unsigned short* __restrict__ hb,
            const float* __restrict__ W, const float* __restrict__ inv,
            const float* __restrict__ scale, const float* __restrict__ shift,
            int do_norm, unsigned short* __restrict__ hwS, int nrows){
  __shared__ unsigned short Wt[128 * WSTRIDE];  // transposed, padded
  int tid = threadIdx.x;
  for (int i = tid; i < 128 * 128; i += 512){
    int k = i >> 7, c = i & 127;
    Wt[c * WSTRIDE + k] = f2bf(W[i]);
  }
  __syncthreads();

  int wave = tid >> 6, lane = tid & 63;
  int r0 = blockIdx.x * 128 + wave * 16;
  int row = r0 + (lane & 15);
  int kg = lane >> 4;
  int rowc = row < nrows ? row : nrows - 1;

  short8 a[4];
  if (do_norm){
#pragma unroll
    for (int kt = 0; kt < 4; ++kt){
      int k0 = kt * 32 + kg * 8;                 // 8 cols within one slice
      int sl = k0 >> 4, o = k0 & 15;
      short8 raw = *(const short8*)(hb + ((long)sl * nrows + rowc) * SLW + o);
      unsigned u[4];
#pragma unroll
      for (int j = 0; j < 4; ++j){
        float lo = bfs2f((unsigned short)raw[2*j]);
        float hi = bfs2f((unsigned short)raw[2*j+1]);
        lo = fmaxf(0.f, lo * scale[k0+2*j]   + shift[k0+2*j]);
        hi = fmaxf(0.f, hi * scale[k0+2*j+1] + shift[k0+2*j+1]);
        u[j] = cvtpk(lo, hi);
      }
      a[kt] = *(short8*)u;
    }
  } else {
    const float* hrow = hf + (long)rowc * D;
#pragma unroll
    for (int kt = 0; kt < 4; ++kt){
      int k0 = kt * 32 + kg * 8;
      f32x4 v0 = *(const f32x4*)(hrow + k0);
      f32x4 v1 = *(const f32x4*)(hrow + k0 + 4);
      unsigned u[4];
      u[0] = cvtpk(v0[0], v0[1]);
      u[1] = cvtpk(v0[2], v0[3]);
      u[2] = cvtpk(v1[0], v1[1]);
      u[3] = cvtpk(v1[2], v1[3]);
      a[kt] = *(short8*)u;
    }
  }

  f32x4 acc[8] = {};
#pragma unroll
  for (int ct = 0; ct < 8; ++ct){
    int col = ct * 16 + (lane & 15);
    const unsigned short* bp = &Wt[col * WSTRIDE + kg * 8];
#pragma unroll
    for (int kt = 0; kt < 4; ++kt){
      short8 b = *(const short8*)(bp + kt * 32);
      acc[ct] = __builtin_amdgcn_mfma_f32_16x16x32_bf16(a[kt], b, acc[ct], 0, 0, 0);
    }
  }

  int colbase = lane & 15;
  int rowo = r0 + kg * 4;
  float ivr[4];
#pragma unroll
  for (int r = 0; r < 4; ++r) ivr[r] = inv[min(rowo + r, nrows - 1)];
#pragma unroll
  for (int ct = 0; ct < 8; ++ct){        // slice = ct (cols ct*16..ct*16+15)
#pragma unroll
    for (int r = 0; r < 4; ++r){
      int rr = rowo + r;
      if (rr < nrows)
        hwS[((long)ct * nrows + rr) * SLW + colbase] = f2bf(acc[ct][r] * ivr[r]);
    }
  }
}

// ---------------- aggregate + BN partial stats (column-sliced) -------------
// slice g = blockIdx%8 rides round-robin dispatch -> one XCD -> 3.2 MB slice
// is L2-resident. Uniform SGPR slice base + 32-bit offsets; f32x2 (pk) math;
// v_cvt_pk_bf16_f32 flush pack.
__global__ __launch_bounds__(256)
void k_agg(const unsigned short* __restrict__ hwS, const float* __restrict__ inv,
           const int* __restrict__ offs, const int* __restrict__ csrc,
           const float* __restrict__ bias,
           unsigned* __restrict__ aggS, float* __restrict__ stats, int n,
           int ngroups){
  int g   = blockIdx.x & 7;
  int grp = blockIdx.x >> 3;
  int tid = threadIdx.x, lane = tid & 63, wv = tid >> 6;
  int eg = lane >> 3;          // edge slot 0..7
  int cp = lane & 7;           // col pair 0..7
  int nwaves = ngroups * 4;
  int gw = grp * 4 + wv;
  int per = (n + nwaves - 1) / nwaves;
  int n0 = min(gw * per, n), n1 = min(n0 + per, n);

  const unsigned* slice = (const unsigned*)hwS + (long)g * n * 8;  // uniform
  unsigned* oslice = aggS + (long)g * n * 8;                       // uniform

  f32x2 bb; bb[0] = bias[g * 16 + cp * 2]; bb[1] = bias[g * 16 + cp * 2 + 1];
  f32x2 ssum = {0.f, 0.f}, qsum = {0.f, 0.f};

  for (int nd = n0; nd < n1; ++nd){
    float ivd = inv[nd];
    unsigned selfv = slice[nd * 8 + cp];
    f32x2 accA = {0.f, 0.f}, accB = {0.f, 0.f};
    int e = offs[nd], ee = offs[nd + 1];
    for (; e + 16 <= ee; e += 16){
      int sA = csrc[e + eg];
      int sB = csrc[e + 8 + eg];
      unsigned vA = slice[sA * 8 + cp];
      unsigned vB = slice[sB * 8 + cp];
      f32x2 uA; uA[0] = bflo2f(vA); uA[1] = bfhi2f(vA);
      f32x2 uB; uB[0] = bflo2f(vB); uB[1] = bfhi2f(vB);
      accA += uA; accB += uB;
    }
    if (e < ee){
      int last = ee - 1;
      int iA = e + eg, iB = e + 8 + eg;
      bool okA = iA < ee, okB = iB < ee;
      unsigned vA = slice[csrc[okA ? iA : last] * 8 + cp];
      unsigned vB = slice[csrc[okB ? iB : last] * 8 + cp];
      vA = okA ? vA : 0u;
      vB = okB ? vB : 0u;
      f32x2 uA; uA[0] = bflo2f(vA); uA[1] = bfhi2f(vA);
      f32x2 uB; uB[0] = bflo2f(vB); uB[1] = bfhi2f(vB);
      accA += uA; accB += uB;
    }
    accA += accB;
    // butterfly across the 8 edge slots (lane bits 3..5)
    f32x2 t;
    t[0] = __shfl_xor(accA[0], 8, 64);  t[1] = __shfl_xor(accA[1], 8, 64);  accA += t;
    t[0] = __shfl_xor(accA[0], 16, 64); t[1] = __shfl_xor(accA[1], 16, 64); accA += t;
    t[0] = __shfl_xor(accA[0], 32, 64); t[1] = __shfl_xor(accA[1], 32, 64); accA += t;
    if (eg == 0){
      f32x2 sv; sv[0] = bflo2f(selfv); sv[1] = bfhi2f(selfv);
      accA += sv;
      f32x2 iv2; iv2[0] = ivd; iv2[1] = ivd;
      accA = accA * iv2 + bb;
      unsigned pk = cvtpk(accA[0], accA[1]);
      __builtin_nontemporal_store(pk, oslice + nd * 8 + cp);
      ssum += accA; qsum += accA * accA;
    }
  }

  __shared__ float red[4][8][4];
  if (eg == 0){
    red[wv][cp][0] = ssum[0]; red[wv][cp][1] = ssum[1];
    red[wv][cp][2] = qsum[0]; red[wv][cp][3] = qsum[1];
  }
  __syncthreads();
  if (tid < 8){
    float t0 = 0, t1 = 0, t2 = 0, t3 = 0;
#pragma unroll
    for (int w = 0; w < 4; ++w){
      t0 += red[w][tid][0]; t1 += red[w][tid][1];
      t2 += red[w][tid][2]; t3 += red[w][tid][3];
    }
    int c = g * 16 + tid * 2;
    atomicAdd(&stats[c],           t0);
    atomicAdd(&stats[c + 1],       t1);
    atomicAdd(&stats[128 + c],     t2);
    atomicAdd(&stats[128 + c + 1], t3);
  }
}

// ---------------- BN finalize ----------------
__global__ void k_bn(const float* __restrict__ stats, const float* __restrict__ gamma,
                     const float* __restrict__ beta, float* __restrict__ scale,
                     float* __restrict__ shift, float invn){
  int c = threadIdx.x;
  float mean = stats[c] * invn;
  float var = stats[128 + c] * invn - mean * mean;
  float isd = rsqrtf(var + 1e-5f);
  float sc = gamma[c] * isd;
  scale[c] = sc;
  shift[c] = beta[c] - mean * sc;
}

// ---------------- pool (fused BN+ReLU of last layer, sliced bf16 agg) ------
__global__ __launch_bounds__(256)
void k_pool(const unsigned* __restrict__ aggS, const float* __restrict__ scale,
            const float* __restrict__ shift, const int* __restrict__ batch,
            float* __restrict__ out, int n){
  int tid = threadIdx.x, lane = tid & 63, wv = tid >> 6;
  int gw = blockIdx.x * 4 + wv;
  int n0 = gw * 64;
  if (n0 >= n) return;
  int n1 = min(n0 + 64, n);
  int c0 = lane * 2;
  int sl = lane >> 3, cp = lane & 7;
  long sbase = (long)sl * n * 8;
  float sc0 = scale[c0], sc1 = scale[c0 + 1];
  float sh0 = shift[c0], sh1 = shift[c0 + 1];
  int g = batch[n0];
  float a0 = 0, a1 = 0;
  for (int nd = n0; nd < n1; ++nd){
    int gn = batch[nd];
    if (gn != g){
      atomicAdd(&out[(long)g * D + c0],     a0);
      atomicAdd(&out[(long)g * D + c0 + 1], a1);
      a0 = 0; a1 = 0; g = gn;
    }
    unsigned v = aggS[sbase + (long)nd * 8 + cp];
    a0 += fmaxf(0.f, bflo2f(v) * sc0 + sh0);
    a1 += fmaxf(0.f, bfhi2f(v) * sc1 + sh1);
  }
  atomicAdd(&out[(long)g * D + c0],     a0);
  atomicAdd(&out[(long)g * D + c0 + 1], a1);
}

extern "C" void kernel_launch(void* const* d_in, const int* in_sizes, int n_in,
                              void* d_out, int out_size, void* d_ws, size_t ws_size,
                              hipStream_t stream){
  const float* x      = (const float*)d_in[0];
  const int*   ei     = (const int*)d_in[1];
  const int*   batch  = (const int*)d_in[2];
  const float* Ws     = (const float*)d_in[3];
  const float* bs     = (const float*)d_in[4];
  const float* gammas = (const float*)d_in[5];
  const float* betas  = (const float*)d_in[6];

  const int E_ = in_sizes[1] / 2;
  const int N_ = in_sizes[2];
  const int* src = ei;
  const int* dst = ei + E_;

  char* p = (char*)d_ws;
  auto alloc = [&](size_t bytes) -> void* {
    void* r = (void*)p;
    p += (bytes + 255) & ~(size_t)255;
    return r;
  };
  unsigned*       bufA   = (unsigned*)      alloc((size_t)N_ * D * 2);   // bf16 agg, sliced
  unsigned short* hwS    = (unsigned short*)alloc((size_t)N_ * D * 2);   // bf16 hw, sliced
  int*            deg    = (int*)           alloc((size_t)N_ * 4);
  float*          inv    = (float*)         alloc((size_t)N_ * 4);
  int*            offs   = (int*)           alloc((size_t)(N_ + 1) * 4);
  int*            cursor = (int*)           alloc((size_t)N_ * 4);
  int*            csrc   = (int*)           alloc((size_t)E_ * 4);
  float*          stats  = (float*)         alloc(3 * 256 * 4);
  float*          scales = (float*)         alloc(3 * 128 * 4);
  float*          shifts = (float*)         alloc(3 * 128 * 4);
  int*            csum   = (int*)           alloc(256 * 4);

  hipMemsetAsync(deg,    0, (size_t)N_ * 4, stream);
  hipMemsetAsync(cursor, 0, (size_t)N_ * 4, stream);
  hipMemsetAsync(stats,  0, 3 * 256 * 4, stream);
  hipMemsetAsync(d_out,  0, (size_t)out_size * 4, stream);

  int nchunks = (N_ + CHUNK - 1) / CHUNK;
  k_deg       <<<(E_ + 255) / 256, 256, 0, stream>>>(dst, deg, E_);
  k_chunksum  <<<nchunks, 256, 0, stream>>>(deg, csum, N_);
  k_scanchunks<<<1, 256, 0, stream>>>(csum, nchunks);
  k_offsets   <<<nchunks, 256, 0, stream>>>(deg, csum, offs, inv, N_);
  k_csrfill   <<<(E_ + 255) / 256, 256, 0, stream>>>(src, dst, offs, cursor, csrc, E_);

  int gemm_blocks = (N_ + 127) / 128;
  int ngroups = 256;                       // k_agg grid = ngroups*8 blocks
  for (int l = 0; l < 3; ++l){
    const float* sc = (l == 0) ? nullptr : scales + (l - 1) * 128;
    const float* sh = (l == 0) ? nullptr : shifts + (l - 1) * 128;
    k_gemm<<<gemm_blocks, 512, 0, stream>>>(x, (const unsigned short*)bufA,
                                            Ws + (size_t)l * D * D, inv, sc, sh,
                                            (l == 0) ? 0 : 1, hwS, N_);
    k_agg<<<ngroups * 8, 256, 0, stream>>>(hwS, inv, offs, csrc, bs + (size_t)l * D,
                                           bufA, stats + (size_t)l * 256, N_, ngroups);
    k_bn<<<1, 128, 0, stream>>>(stats + (size_t)l * 256, gammas + (size_t)l * D,
                                betas + (size_t)l * D, scales + (size_t)l * 128,
                                shifts + (size_t)l * 128, 1.0f / (float)N_);
  }
  k_pool<<<(N_ + 255) / 256, 256, 0, stream>>>(bufA, scales + 2 * 128, shifts + 2 * 128,
                                               batch, (float*)d_out, N_);
}

// Round 9
// 681.120 us; speedup vs baseline: 1.1803x; 1.1803x over previous
//
#include <hip/hip_runtime.h>

#define D 128
#define CHUNK 512
#define NSLICE 8
#define SLW 16            // cols per slice

using short8 = __attribute__((ext_vector_type(8))) short;
using f32x4  = __attribute__((ext_vector_type(4))) float;
using f32x2  = __attribute__((ext_vector_type(2))) float;

__device__ __forceinline__ unsigned short f2bf(float f){
  unsigned u = __builtin_bit_cast(unsigned, f);
  u += 0x7fffu + ((u >> 16) & 1u);           // round-to-nearest-even
  return (unsigned short)(u >> 16);
}
__device__ __forceinline__ float bflo2f(unsigned v){
  return __builtin_bit_cast(float, v << 16);
}
__device__ __forceinline__ float bfhi2f(unsigned v){
  return __builtin_bit_cast(float, v & 0xffff0000u);
}
__device__ __forceinline__ float bfs2f(unsigned short v){
  return __builtin_bit_cast(float, ((unsigned)v) << 16);
}
// packed f32x2 -> 2xbf16 in one instruction (gfx950)
__device__ __forceinline__ unsigned cvtpk(float lo, float hi){
  unsigned r;
  asm("v_cvt_pk_bf16_f32 %0, %1, %2" : "=v"(r) : "v"(lo), "v"(hi));
  return r;
}

// ---------------- degree ----------------
__global__ void k_deg(const int* __restrict__ dst, int* __restrict__ deg, int E){
  int e = blockIdx.x * 256 + threadIdx.x;
  if (e < E) atomicAdd(&deg[dst[e]], 1);
}

// ---------------- scan (3-stage) ----------------
__global__ void k_chunksum(const int* __restrict__ deg, int* __restrict__ csum, int n){
  __shared__ int s[256];
  int tid = threadIdx.x;
  int n0 = blockIdx.x * CHUNK + tid * 2;
  int v = 0;
  if (n0     < n) v += deg[n0];
  if (n0 + 1 < n) v += deg[n0 + 1];
  s[tid] = v; __syncthreads();
  for (int off = 128; off > 0; off >>= 1){
    if (tid < off) s[tid] += s[tid + off];
    __syncthreads();
  }
  if (tid == 0) csum[blockIdx.x] = s[0];
}

__global__ void k_scanchunks(int* __restrict__ csum, int nchunks){
  __shared__ int s[256];
  int tid = threadIdx.x;
  int v = (tid < nchunks) ? csum[tid] : 0;
  s[tid] = v; __syncthreads();
  for (int off = 1; off < 256; off <<= 1){
    int t = (tid >= off) ? s[tid - off] : 0;
    __syncthreads();
    s[tid] += t;
    __syncthreads();
  }
  if (tid < nchunks) csum[tid] = s[tid] - v;   // exclusive
}

__global__ void k_offsets(const int* __restrict__ deg, const int* __restrict__ csum,
                          int* __restrict__ offs, float* __restrict__ inv, int n){
  __shared__ int s[256];
  int tid = threadIdx.x;
  int n0 = blockIdx.x * CHUNK + tid * 2;
  int d0 = (n0     < n) ? deg[n0]     : 0;
  int d1 = (n0 + 1 < n) ? deg[n0 + 1] : 0;
  int pair = d0 + d1;
  s[tid] = pair; __syncthreads();
  for (int off = 1; off < 256; off <<= 1){
    int t = (tid >= off) ? s[tid - off] : 0;
    __syncthreads();
    s[tid] += t;
    __syncthreads();
  }
  int excl = s[tid] - pair + csum[blockIdx.x];
  if (n0     <= n) offs[n0]     = excl;
  if (n0 + 1 <= n) offs[n0 + 1] = excl + d0;
  if (n0     < n) inv[n0]     = rsqrtf((float)(d0 + 1));
  if (n0 + 1 < n) inv[n0 + 1] = rsqrtf((float)(d1 + 1));
}

// ---------------- CSR fill (index only — weight folded into hw rows) ------
__global__ void k_csrfill(const int* __restrict__ src, const int* __restrict__ dst,
                          const int* __restrict__ offs, int* __restrict__ cursor,
                          int* __restrict__ csrc, int E){
  int e = blockIdx.x * 256 + threadIdx.x;
  if (e >= E) return;
  int s = src[e], d = dst[e];
  int pos = offs[d] + atomicAdd(&cursor[d], 1);
  csrc[pos] = s;
}

// ---------------- GEMM: hwS(bf16, slice-major) = act(hin) @ W, rows × inv --
// hwS layout: [slice][N][16] ushorts. agg input (do_norm) also slice-major.
#define WSTRIDE 136
__global__ __launch_bounds__(512)
void k_gemm(const float* __restrict__ hf, const unsigned short* __restrict__ hb,
            const float* __restrict__ W, const float* __restrict__ inv,
            const float* __restrict__ scale, const float* __restrict__ shift,
            int do_norm, unsigned short* __restrict__ hwS, int nrows){
  __shared__ unsigned short Wt[128 * WSTRIDE];  // transposed, padded
  int tid = threadIdx.x;
  for (int i = tid; i < 128 * 128; i += 512){
    int k = i >> 7, c = i & 127;
    Wt[c * WSTRIDE + k] = f2bf(W[i]);
  }
  __syncthreads();

  int wave = tid >> 6, lane = tid & 63;
  int r0 = blockIdx.x * 128 + wave * 16;
  int row = r0 + (lane & 15);
  int kg = lane >> 4;
  int rowc = row < nrows ? row : nrows - 1;

  short8 a[4];
  if (do_norm){
#pragma unroll
    for (int kt = 0; kt < 4; ++kt){
      int k0 = kt * 32 + kg * 8;                 // 8 cols within one slice
      int sl = k0 >> 4, o = k0 & 15;
      short8 raw = *(const short8*)(hb + ((long)sl * nrows + rowc) * SLW + o);
      unsigned u[4];
#pragma unroll
      for (int j = 0; j < 4; ++j){
        float lo = bfs2f((unsigned short)raw[2*j]);
        float hi = bfs2f((unsigned short)raw[2*j+1]);
        lo = fmaxf(0.f, lo * scale[k0+2*j]   + shift[k0+2*j]);
        hi = fmaxf(0.f, hi * scale[k0+2*j+1] + shift[k0+2*j+1]);
        u[j] = cvtpk(lo, hi);
      }
      a[kt] = *(short8*)u;
    }
  } else {
    const float* hrow = hf + (long)rowc * D;
#pragma unroll
    for (int kt = 0; kt < 4; ++kt){
      int k0 = kt * 32 + kg * 8;
      f32x4 v0 = *(const f32x4*)(hrow + k0);
      f32x4 v1 = *(const f32x4*)(hrow + k0 + 4);
      unsigned u[4];
      u[0] = cvtpk(v0[0], v0[1]);
      u[1] = cvtpk(v0[2], v0[3]);
      u[2] = cvtpk(v1[0], v1[1]);
      u[3] = cvtpk(v1[2], v1[3]);
      a[kt] = *(short8*)u;
    }
  }

  f32x4 acc[8] = {};
#pragma unroll
  for (int ct = 0; ct < 8; ++ct){
    int col = ct * 16 + (lane & 15);
    const unsigned short* bp = &Wt[col * WSTRIDE + kg * 8];
#pragma unroll
    for (int kt = 0; kt < 4; ++kt){
      short8 b = *(const short8*)(bp + kt * 32);
      acc[ct] = __builtin_amdgcn_mfma_f32_16x16x32_bf16(a[kt], b, acc[ct], 0, 0, 0);
    }
  }

  int colbase = lane & 15;
  int rowo = r0 + kg * 4;
  float ivr[4];
#pragma unroll
  for (int r = 0; r < 4; ++r) ivr[r] = inv[min(rowo + r, nrows - 1)];
#pragma unroll
  for (int ct = 0; ct < 8; ++ct){        // slice = ct (cols ct*16..ct*16+15)
#pragma unroll
    for (int r = 0; r < 4; ++r){
      int rr = rowo + r;
      if (rr < nrows)
        hwS[((long)ct * nrows + rr) * SLW + colbase] = f2bf(acc[ct][r] * ivr[r]);
    }
  }
}

// ---------------- aggregate + BN partial stats (sliced, node-cohort) -------
// slice g = blockIdx%8 -> one XCD (round-robin dispatch), 3.2 MB L2-resident.
// lane = node-slot(ns,8) x colpair(cp,8): 8 consecutive nodes in parallel,
// 8 lanes each. No per-node butterfly; 2 edges/iter with index prefetch.
__global__ __launch_bounds__(256)
void k_agg(const unsigned short* __restrict__ hwS, const float* __restrict__ inv,
           const int* __restrict__ offs, const int* __restrict__ csrc,
           const float* __restrict__ bias,
           unsigned* __restrict__ aggS, float* __restrict__ stats, int n,
           int ngroups){
  int g   = blockIdx.x & 7;
  int grp = blockIdx.x >> 3;
  int tid = threadIdx.x, lane = tid & 63, wv = tid >> 6;
  int ns = lane >> 3;          // node slot 0..7
  int cp = lane & 7;           // col pair 0..7
  int nwaves = ngroups * 4;
  int gw = grp * 4 + wv;
  int per = (n + nwaves - 1) / nwaves;
  int n0 = min(gw * per, n), n1 = min(n0 + per, n);

  const unsigned* slice = (const unsigned*)hwS + (long)g * n * 8;  // uniform
  unsigned* oslice = aggS + (long)g * n * 8;                       // uniform

  float b0 = bias[g * 16 + cp * 2], b1 = bias[g * 16 + cp * 2 + 1];
  float s0 = 0, s1 = 0, q0 = 0, q1 = 0;

  for (int base = n0; base < n1; base += 8){
    int node = base + ns;
    bool act = node < n1;
    int ndc = act ? node : n1 - 1;
    int e  = offs[ndc];
    int ee = offs[ndc + 1];
    float a0 = 0, a1 = 0;

    int p0 = (e     < ee) ? e     : 0;
    int p1 = (e + 1 < ee) ? e + 1 : 0;
    int i0 = csrc[p0];
    int i1 = csrc[p1];
    while (__any(e < ee)){
      bool ok0 = e < ee, ok1 = e + 1 < ee;
      int q0i = (e + 2 < ee) ? e + 2 : 0;
      int q1i = (e + 3 < ee) ? e + 3 : 0;
      int j0 = csrc[q0i];
      int j1 = csrc[q1i];
      unsigned v0 = slice[i0 * 8 + cp];
      unsigned v1 = slice[i1 * 8 + cp];
      v0 = ok0 ? v0 : 0u;
      v1 = ok1 ? v1 : 0u;
      a0 += bflo2f(v0) + bflo2f(v1);
      a1 += bfhi2f(v0) + bfhi2f(v1);
      i0 = j0; i1 = j1;
      e += 2;
    }

    if (act){
      unsigned selfv = slice[node * 8 + cp];
      float ivd = inv[node];
      a0 = (a0 + bflo2f(selfv)) * ivd + b0;
      a1 = (a1 + bfhi2f(selfv)) * ivd + b1;
      unsigned pk = ((unsigned)f2bf(a1) << 16) | (unsigned)f2bf(a0);
      __builtin_nontemporal_store(pk, oslice + node * 8 + cp);
      s0 += a0; s1 += a1; q0 += a0 * a0; q1 += a1 * a1;
    }
  }

  // fold the 8 node slots (lane bits 3..5) once per kernel
  s0 += __shfl_xor(s0, 8, 64);  s1 += __shfl_xor(s1, 8, 64);
  q0 += __shfl_xor(q0, 8, 64);  q1 += __shfl_xor(q1, 8, 64);
  s0 += __shfl_xor(s0, 16, 64); s1 += __shfl_xor(s1, 16, 64);
  q0 += __shfl_xor(q0, 16, 64); q1 += __shfl_xor(q1, 16, 64);
  s0 += __shfl_xor(s0, 32, 64); s1 += __shfl_xor(s1, 32, 64);
  q0 += __shfl_xor(q0, 32, 64); q1 += __shfl_xor(q1, 32, 64);

  __shared__ float red[4][8][4];
  if (ns == 0){
    red[wv][cp][0] = s0; red[wv][cp][1] = s1;
    red[wv][cp][2] = q0; red[wv][cp][3] = q1;
  }
  __syncthreads();
  if (tid < 8){
    float t0 = 0, t1 = 0, t2 = 0, t3 = 0;
#pragma unroll
    for (int w = 0; w < 4; ++w){
      t0 += red[w][tid][0]; t1 += red[w][tid][1];
      t2 += red[w][tid][2]; t3 += red[w][tid][3];
    }
    int c = g * 16 + tid * 2;
    atomicAdd(&stats[c],           t0);
    atomicAdd(&stats[c + 1],       t1);
    atomicAdd(&stats[128 + c],     t2);
    atomicAdd(&stats[128 + c + 1], t3);
  }
}

// ---------------- BN finalize ----------------
__global__ void k_bn(const float* __restrict__ stats, const float* __restrict__ gamma,
                     const float* __restrict__ beta, float* __restrict__ scale,
                     float* __restrict__ shift, float invn){
  int c = threadIdx.x;
  float mean = stats[c] * invn;
  float var = stats[128 + c] * invn - mean * mean;
  float isd = rsqrtf(var + 1e-5f);
  float sc = gamma[c] * isd;
  scale[c] = sc;
  shift[c] = beta[c] - mean * sc;
}

// ---------------- pool (fused BN+ReLU of last layer, sliced bf16 agg) ------
__global__ __launch_bounds__(256)
void k_pool(const unsigned* __restrict__ aggS, const float* __restrict__ scale,
            const float* __restrict__ shift, const int* __restrict__ batch,
            float* __restrict__ out, int n){
  int tid = threadIdx.x, lane = tid & 63, wv = tid >> 6;
  int gw = blockIdx.x * 4 + wv;
  int n0 = gw * 64;
  if (n0 >= n) return;
  int n1 = min(n0 + 64, n);
  int c0 = lane * 2;
  int sl = lane >> 3, cp = lane & 7;
  long sbase = (long)sl * n * 8;
  float sc0 = scale[c0], sc1 = scale[c0 + 1];
  float sh0 = shift[c0], sh1 = shift[c0 + 1];
  int g = batch[n0];
  float a0 = 0, a1 = 0;
  for (int nd = n0; nd < n1; ++nd){
    int gn = batch[nd];
    if (gn != g){
      atomicAdd(&out[(long)g * D + c0],     a0);
      atomicAdd(&out[(long)g * D + c0 + 1], a1);
      a0 = 0; a1 = 0; g = gn;
    }
    unsigned v = aggS[sbase + (long)nd * 8 + cp];
    a0 += fmaxf(0.f, bflo2f(v) * sc0 + sh0);
    a1 += fmaxf(0.f, bfhi2f(v) * sc1 + sh1);
  }
  atomicAdd(&out[(long)g * D + c0],     a0);
  atomicAdd(&out[(long)g * D + c0 + 1], a1);
}

extern "C" void kernel_launch(void* const* d_in, const int* in_sizes, int n_in,
                              void* d_out, int out_size, void* d_ws, size_t ws_size,
                              hipStream_t stream){
  const float* x      = (const float*)d_in[0];
  const int*   ei     = (const int*)d_in[1];
  const int*   batch  = (const int*)d_in[2];
  const float* Ws     = (const float*)d_in[3];
  const float* bs     = (const float*)d_in[4];
  const float* gammas = (const float*)d_in[5];
  const float* betas  = (const float*)d_in[6];

  const int E_ = in_sizes[1] / 2;
  const int N_ = in_sizes[2];
  const int* src = ei;
  const int* dst = ei + E_;

  char* p = (char*)d_ws;
  auto alloc = [&](size_t bytes) -> void* {
    void* r = (void*)p;
    p += (bytes + 255) & ~(size_t)255;
    return r;
  };
  unsigned*       bufA   = (unsigned*)      alloc((size_t)N_ * D * 2);   // bf16 agg, sliced
  unsigned short* hwS    = (unsigned short*)alloc((size_t)N_ * D * 2);   // bf16 hw, sliced
  int*            deg    = (int*)           alloc((size_t)N_ * 4);
  float*          inv    = (float*)         alloc((size_t)N_ * 4);
  int*            offs   = (int*)           alloc((size_t)(N_ + 1) * 4);
  int*            cursor = (int*)           alloc((size_t)N_ * 4);
  int*            csrc   = (int*)           alloc((size_t)E_ * 4);
  float*          stats  = (float*)         alloc(3 * 256 * 4);
  float*          scales = (float*)         alloc(3 * 128 * 4);
  float*          shifts = (float*)         alloc(3 * 128 * 4);
  int*            csum   = (int*)           alloc(256 * 4);

  hipMemsetAsync(deg,    0, (size_t)N_ * 4, stream);
  hipMemsetAsync(cursor, 0, (size_t)N_ * 4, stream);
  hipMemsetAsync(stats,  0, 3 * 256 * 4, stream);
  hipMemsetAsync(d_out,  0, (size_t)out_size * 4, stream);

  int nchunks = (N_ + CHUNK - 1) / CHUNK;
  k_deg       <<<(E_ + 255) / 256, 256, 0, stream>>>(dst, deg, E_);
  k_chunksum  <<<nchunks, 256, 0, stream>>>(deg, csum, N_);
  k_scanchunks<<<1, 256, 0, stream>>>(csum, nchunks);
  k_offsets   <<<nchunks, 256, 0, stream>>>(deg, csum, offs, inv, N_);
  k_csrfill   <<<(E_ + 255) / 256, 256, 0, stream>>>(src, dst, offs, cursor, csrc, E_);

  int gemm_blocks = (N_ + 127) / 128;
  int ngroups = 256;                       // k_agg grid = ngroups*8 blocks
  for (int l = 0; l < 3; ++l){
    const float* sc = (l == 0) ? nullptr : scales + (l - 1) * 128;
    const float* sh = (l == 0) ? nullptr : shifts + (l - 1) * 128;
    k_gemm<<<gemm_blocks, 512, 0, stream>>>(x, (const unsigned short*)bufA,
                                            Ws + (size_t)l * D * D, inv, sc, sh,
                                            (l == 0) ? 0 : 1, hwS, N_);
    k_agg<<<ngroups * 8, 256, 0, stream>>>(hwS, inv, offs, csrc, bs + (size_t)l * D,
                                           bufA, stats + (size_t)l * 256, N_, ngroups);
    k_bn<<<1, 128, 0, stream>>>(stats + (size_t)l * 256, gammas + (size_t)l * D,
                                betas + (size_t)l * D, scales + (size_t)l * 128,
                                shifts + (size_t)l * 128, 1.0f / (float)N_);
  }
  k_pool<<<(N_ + 255) / 256, 256, 0, stream>>>(bufA, scales + 2 * 128, shifts + 2 * 128,
                                               batch, (float*)d_out, N_);
}

// Round 10
// 581.969 us; speedup vs baseline: 1.3814x; 1.1704x over previous
//
#include <hip/hip_runtime.h>

#define D 128
#define CHUNK 512
#define NSLICE 8
#define SLW 16            // cols per slice

using short8 = __attribute__((ext_vector_type(8))) short;
using f32x4  = __attribute__((ext_vector_type(4))) float;
using f32x2  = __attribute__((ext_vector_type(2))) float;

__device__ __forceinline__ unsigned short f2bf(float f){
  unsigned u = __builtin_bit_cast(unsigned, f);
  u += 0x7fffu + ((u >> 16) & 1u);           // round-to-nearest-even
  return (unsigned short)(u >> 16);
}
__device__ __forceinline__ float bflo2f(unsigned v){
  return __builtin_bit_cast(float, v << 16);
}
__device__ __forceinline__ float bfhi2f(unsigned v){
  return __builtin_bit_cast(float, v & 0xffff0000u);
}
__device__ __forceinline__ float bfs2f(unsigned short v){
  return __builtin_bit_cast(float, ((unsigned)v) << 16);
}
// packed f32x2 -> 2xbf16 in one instruction (gfx950)
__device__ __forceinline__ unsigned cvtpk(float lo, float hi){
  unsigned r;
  asm("v_cvt_pk_bf16_f32 %0, %1, %2" : "=v"(r) : "v"(lo), "v"(hi));
  return r;
}

// ---------------- degree ----------------
__global__ void k_deg(const int* __restrict__ dst, int* __restrict__ deg, int E){
  int e = blockIdx.x * 256 + threadIdx.x;
  if (e < E) atomicAdd(&deg[dst[e]], 1);
}

// ---------------- scan (3-stage) ----------------
__global__ void k_chunksum(const int* __restrict__ deg, int* __restrict__ csum, int n){
  __shared__ int s[256];
  int tid = threadIdx.x;
  int n0 = blockIdx.x * CHUNK + tid * 2;
  int v = 0;
  if (n0     < n) v += deg[n0];
  if (n0 + 1 < n) v += deg[n0 + 1];
  s[tid] = v; __syncthreads();
  for (int off = 128; off > 0; off >>= 1){
    if (tid < off) s[tid] += s[tid + off];
    __syncthreads();
  }
  if (tid == 0) csum[blockIdx.x] = s[0];
}

__global__ void k_scanchunks(int* __restrict__ csum, int nchunks){
  __shared__ int s[256];
  int tid = threadIdx.x;
  int v = (tid < nchunks) ? csum[tid] : 0;
  s[tid] = v; __syncthreads();
  for (int off = 1; off < 256; off <<= 1){
    int t = (tid >= off) ? s[tid - off] : 0;
    __syncthreads();
    s[tid] += t;
    __syncthreads();
  }
  if (tid < nchunks) csum[tid] = s[tid] - v;   // exclusive
}

__global__ void k_offsets(const int* __restrict__ deg, const int* __restrict__ csum,
                          int* __restrict__ offs, float* __restrict__ inv, int n){
  __shared__ int s[256];
  int tid = threadIdx.x;
  int n0 = blockIdx.x * CHUNK + tid * 2;
  int d0 = (n0     < n) ? deg[n0]     : 0;
  int d1 = (n0 + 1 < n) ? deg[n0 + 1] : 0;
  int pair = d0 + d1;
  s[tid] = pair; __syncthreads();
  for (int off = 1; off < 256; off <<= 1){
    int t = (tid >= off) ? s[tid - off] : 0;
    __syncthreads();
    s[tid] += t;
    __syncthreads();
  }
  int excl = s[tid] - pair + csum[blockIdx.x];
  if (n0     <= n) offs[n0]     = excl;
  if (n0 + 1 <= n) offs[n0 + 1] = excl + d0;
  if (n0     < n) inv[n0]     = rsqrtf((float)(d0 + 1));
  if (n0 + 1 < n) inv[n0 + 1] = rsqrtf((float)(d1 + 1));
}

// ---------------- CSR fill (index only — weight folded into hw rows) ------
__global__ void k_csrfill(const int* __restrict__ src, const int* __restrict__ dst,
                          const int* __restrict__ offs, int* __restrict__ cursor,
                          int* __restrict__ csrc, int E){
  int e = blockIdx.x * 256 + threadIdx.x;
  if (e >= E) return;
  int s = src[e], d = dst[e];
  int pos = offs[d] + atomicAdd(&cursor[d], 1);
  csrc[pos] = s;
}

// ---------------- GEMM: hwS(bf16, slice-major) = act(hin) @ W, rows × inv --
// hwS layout: [slice][N][16] ushorts. agg input (do_norm) also slice-major.
#define WSTRIDE 136
__global__ __launch_bounds__(512)
void k_gemm(const float* __restrict__ hf, const unsigned short* __restrict__ hb,
            const float* __restrict__ W, const float* __restrict__ inv,
            const float* __restrict__ scale, const float* __restrict__ shift,
            int do_norm, unsigned short* __restrict__ hwS, int nrows){
  __shared__ unsigned short Wt[128 * WSTRIDE];  // transposed, padded
  int tid = threadIdx.x;
  for (int i = tid; i < 128 * 128; i += 512){
    int k = i >> 7, c = i & 127;
    Wt[c * WSTRIDE + k] = f2bf(W[i]);
  }
  __syncthreads();

  int wave = tid >> 6, lane = tid & 63;
  int r0 = blockIdx.x * 128 + wave * 16;
  int row = r0 + (lane & 15);
  int kg = lane >> 4;
  int rowc = row < nrows ? row : nrows - 1;

  short8 a[4];
  if (do_norm){
#pragma unroll
    for (int kt = 0; kt < 4; ++kt){
      int k0 = kt * 32 + kg * 8;                 // 8 cols within one slice
      int sl = k0 >> 4, o = k0 & 15;
      short8 raw = *(const short8*)(hb + ((long)sl * nrows + rowc) * SLW + o);
      unsigned u[4];
#pragma unroll
      for (int j = 0; j < 4; ++j){
        float lo = bfs2f((unsigned short)raw[2*j]);
        float hi = bfs2f((unsigned short)raw[2*j+1]);
        lo = fmaxf(0.f, lo * scale[k0+2*j]   + shift[k0+2*j]);
        hi = fmaxf(0.f, hi * scale[k0+2*j+1] + shift[k0+2*j+1]);
        u[j] = cvtpk(lo, hi);
      }
      a[kt] = *(short8*)u;
    }
  } else {
    const float* hrow = hf + (long)rowc * D;
#pragma unroll
    for (int kt = 0; kt < 4; ++kt){
      int k0 = kt * 32 + kg * 8;
      f32x4 v0 = *(const f32x4*)(hrow + k0);
      f32x4 v1 = *(const f32x4*)(hrow + k0 + 4);
      unsigned u[4];
      u[0] = cvtpk(v0[0], v0[1]);
      u[1] = cvtpk(v0[2], v0[3]);
      u[2] = cvtpk(v1[0], v1[1]);
      u[3] = cvtpk(v1[2], v1[3]);
      a[kt] = *(short8*)u;
    }
  }

  f32x4 acc[8] = {};
#pragma unroll
  for (int ct = 0; ct < 8; ++ct){
    int col = ct * 16 + (lane & 15);
    const unsigned short* bp = &Wt[col * WSTRIDE + kg * 8];
#pragma unroll
    for (int kt = 0; kt < 4; ++kt){
      short8 b = *(const short8*)(bp + kt * 32);
      acc[ct] = __builtin_amdgcn_mfma_f32_16x16x32_bf16(a[kt], b, acc[ct], 0, 0, 0);
    }
  }

  int colbase = lane & 15;
  int rowo = r0 + kg * 4;
  float ivr[4];
#pragma unroll
  for (int r = 0; r < 4; ++r) ivr[r] = inv[min(rowo + r, nrows - 1)];
#pragma unroll
  for (int ct = 0; ct < 8; ++ct){        // slice = ct (cols ct*16..ct*16+15)
#pragma unroll
    for (int r = 0; r < 4; ++r){
      int rr = rowo + r;
      if (rr < nrows)
        hwS[((long)ct * nrows + rr) * SLW + colbase] = f2bf(acc[ct][r] * ivr[r]);
    }
  }
}

// ---------------- aggregate + BN partial stats (sliced, node-cohort) -------
// slice g = blockIdx%8 -> one XCD (round-robin dispatch), 3.2 MB L2-resident.
// lane = node-slot(ns,8) x colpair(cp,8): 8 consecutive nodes in parallel.
// 4 edges/iter, indices prefetched one iteration ahead (4-8 VMEM in flight).
__global__ __launch_bounds__(256)
void k_agg(const unsigned short* __restrict__ hwS, const float* __restrict__ inv,
           const int* __restrict__ offs, const int* __restrict__ csrc,
           const float* __restrict__ bias,
           unsigned* __restrict__ aggS, float* __restrict__ stats, int n,
           int ngroups){
  int g   = blockIdx.x & 7;
  int grp = blockIdx.x >> 3;
  int tid = threadIdx.x, lane = tid & 63, wv = tid >> 6;
  int ns = lane >> 3;          // node slot 0..7
  int cp = lane & 7;           // col pair 0..7
  int nwaves = ngroups * 4;
  int gw = grp * 4 + wv;
  int per = (n + nwaves - 1) / nwaves;
  int n0 = min(gw * per, n), n1 = min(n0 + per, n);

  const unsigned* slice = (const unsigned*)hwS + (long)g * n * 8;  // uniform
  unsigned* oslice = aggS + (long)g * n * 8;                       // uniform

  float b0 = bias[g * 16 + cp * 2], b1 = bias[g * 16 + cp * 2 + 1];
  float s0 = 0, s1 = 0, q0 = 0, q1 = 0;

  for (int base = n0; base < n1; base += 8){
    int node = base + ns;
    bool act = node < n1;
    int ndc = act ? node : n1 - 1;
    int e  = offs[ndc];
    int ee = offs[ndc + 1];
    float a0 = 0, a1 = 0;

    int i0 = csrc[(e     < ee) ? e     : 0];
    int i1 = csrc[(e + 1 < ee) ? e + 1 : 0];
    int i2 = csrc[(e + 2 < ee) ? e + 2 : 0];
    int i3 = csrc[(e + 3 < ee) ? e + 3 : 0];
    while (__any(e < ee)){
      // prefetch next iteration's indices (independent of this iter's gathers)
      int j0 = csrc[(e + 4 < ee) ? e + 4 : 0];
      int j1 = csrc[(e + 5 < ee) ? e + 5 : 0];
      int j2 = csrc[(e + 6 < ee) ? e + 6 : 0];
      int j3 = csrc[(e + 7 < ee) ? e + 7 : 0];
      unsigned v0 = slice[i0 * 8 + cp];
      unsigned v1 = slice[i1 * 8 + cp];
      unsigned v2 = slice[i2 * 8 + cp];
      unsigned v3 = slice[i3 * 8 + cp];
      v0 = (e     < ee) ? v0 : 0u;
      v1 = (e + 1 < ee) ? v1 : 0u;
      v2 = (e + 2 < ee) ? v2 : 0u;
      v3 = (e + 3 < ee) ? v3 : 0u;
      a0 += (bflo2f(v0) + bflo2f(v1)) + (bflo2f(v2) + bflo2f(v3));
      a1 += (bfhi2f(v0) + bfhi2f(v1)) + (bfhi2f(v2) + bfhi2f(v3));
      i0 = j0; i1 = j1; i2 = j2; i3 = j3;
      e += 4;
    }

    if (act){
      unsigned selfv = slice[node * 8 + cp];
      float ivd = inv[node];
      a0 = (a0 + bflo2f(selfv)) * ivd + b0;
      a1 = (a1 + bfhi2f(selfv)) * ivd + b1;
      unsigned pk = ((unsigned)f2bf(a1) << 16) | (unsigned)f2bf(a0);
      __builtin_nontemporal_store(pk, oslice + node * 8 + cp);
      s0 += a0; s1 += a1; q0 += a0 * a0; q1 += a1 * a1;
    }
  }

  // fold the 8 node slots (lane bits 3..5) once per kernel
  s0 += __shfl_xor(s0, 8, 64);  s1 += __shfl_xor(s1, 8, 64);
  q0 += __shfl_xor(q0, 8, 64);  q1 += __shfl_xor(q1, 8, 64);
  s0 += __shfl_xor(s0, 16, 64); s1 += __shfl_xor(s1, 16, 64);
  q0 += __shfl_xor(q0, 16, 64); q1 += __shfl_xor(q1, 16, 64);
  s0 += __shfl_xor(s0, 32, 64); s1 += __shfl_xor(s1, 32, 64);
  q0 += __shfl_xor(q0, 32, 64); q1 += __shfl_xor(q1, 32, 64);

  __shared__ float red[4][8][4];
  if (ns == 0){
    red[wv][cp][0] = s0; red[wv][cp][1] = s1;
    red[wv][cp][2] = q0; red[wv][cp][3] = q1;
  }
  __syncthreads();
  if (tid < 8){
    float t0 = 0, t1 = 0, t2 = 0, t3 = 0;
#pragma unroll
    for (int w = 0; w < 4; ++w){
      t0 += red[w][tid][0]; t1 += red[w][tid][1];
      t2 += red[w][tid][2]; t3 += red[w][tid][3];
    }
    int c = g * 16 + tid * 2;
    atomicAdd(&stats[c],           t0);
    atomicAdd(&stats[c + 1],       t1);
    atomicAdd(&stats[128 + c],     t2);
    atomicAdd(&stats[128 + c + 1], t3);
  }
}

// ---------------- BN finalize ----------------
__global__ void k_bn(const float* __restrict__ stats, const float* __restrict__ gamma,
                     const float* __restrict__ beta, float* __restrict__ scale,
                     float* __restrict__ shift, float invn){
  int c = threadIdx.x;
  float mean = stats[c] * invn;
  float var = stats[128 + c] * invn - mean * mean;
  float isd = rsqrtf(var + 1e-5f);
  float sc = gamma[c] * isd;
  scale[c] = sc;
  shift[c] = beta[c] - mean * sc;
}

// ---------------- pool (fused BN+ReLU of last layer, sliced bf16 agg) ------
__global__ __launch_bounds__(256)
void k_pool(const unsigned* __restrict__ aggS, const float* __restrict__ scale,
            const float* __restrict__ shift, const int* __restrict__ batch,
            float* __restrict__ out, int n){
  int tid = threadIdx.x, lane = tid & 63, wv = tid >> 6;
  int gw = blockIdx.x * 4 + wv;
  int n0 = gw * 64;
  if (n0 >= n) return;
  int n1 = min(n0 + 64, n);
  int c0 = lane * 2;
  int sl = lane >> 3, cp = lane & 7;
  long sbase = (long)sl * n * 8;
  float sc0 = scale[c0], sc1 = scale[c0 + 1];
  float sh0 = shift[c0], sh1 = shift[c0 + 1];
  int g = batch[n0];
  float a0 = 0, a1 = 0;
  for (int nd = n0; nd < n1; ++nd){
    int gn = batch[nd];
    if (gn != g){
      atomicAdd(&out[(long)g * D + c0],     a0);
      atomicAdd(&out[(long)g * D + c0 + 1], a1);
      a0 = 0; a1 = 0; g = gn;
    }
    unsigned v = aggS[sbase + (long)nd * 8 + cp];
    a0 += fmaxf(0.f, bflo2f(v) * sc0 + sh0);
    a1 += fmaxf(0.f, bfhi2f(v) * sc1 + sh1);
  }
  atomicAdd(&out[(long)g * D + c0],     a0);
  atomicAdd(&out[(long)g * D + c0 + 1], a1);
}

extern "C" void kernel_launch(void* const* d_in, const int* in_sizes, int n_in,
                              void* d_out, int out_size, void* d_ws, size_t ws_size,
                              hipStream_t stream){
  const float* x      = (const float*)d_in[0];
  const int*   ei     = (const int*)d_in[1];
  const int*   batch  = (const int*)d_in[2];
  const float* Ws     = (const float*)d_in[3];
  const float* bs     = (const float*)d_in[4];
  const float* gammas = (const float*)d_in[5];
  const float* betas  = (const float*)d_in[6];

  const int E_ = in_sizes[1] / 2;
  const int N_ = in_sizes[2];
  const int* src = ei;
  const int* dst = ei + E_;

  char* p = (char*)d_ws;
  auto alloc = [&](size_t bytes) -> void* {
    void* r = (void*)p;
    p += (bytes + 255) & ~(size_t)255;
    return r;
  };
  unsigned*       bufA   = (unsigned*)      alloc((size_t)N_ * D * 2);   // bf16 agg, sliced
  unsigned short* hwS    = (unsigned short*)alloc((size_t)N_ * D * 2);   // bf16 hw, sliced
  int*            deg    = (int*)           alloc((size_t)N_ * 4);
  float*          inv    = (float*)         alloc((size_t)N_ * 4);
  int*            offs   = (int*)           alloc((size_t)(N_ + 1) * 4);
  int*            cursor = (int*)           alloc((size_t)N_ * 4);
  int*            csrc   = (int*)           alloc((size_t)E_ * 4);
  float*          stats  = (float*)         alloc(3 * 256 * 4);
  float*          scales = (float*)         alloc(3 * 128 * 4);
  float*          shifts = (float*)         alloc(3 * 128 * 4);
  int*            csum   = (int*)           alloc(256 * 4);

  hipMemsetAsync(deg,    0, (size_t)N_ * 4, stream);
  hipMemsetAsync(cursor, 0, (size_t)N_ * 4, stream);
  hipMemsetAsync(stats,  0, 3 * 256 * 4, stream);
  hipMemsetAsync(d_out,  0, (size_t)out_size * 4, stream);

  int nchunks = (N_ + CHUNK - 1) / CHUNK;
  k_deg       <<<(E_ + 255) / 256, 256, 0, stream>>>(dst, deg, E_);
  k_chunksum  <<<nchunks, 256, 0, stream>>>(deg, csum, N_);
  k_scanchunks<<<1, 256, 0, stream>>>(csum, nchunks);
  k_offsets   <<<nchunks, 256, 0, stream>>>(deg, csum, offs, inv, N_);
  k_csrfill   <<<(E_ + 255) / 256, 256, 0, stream>>>(src, dst, offs, cursor, csrc, E_);

  int gemm_blocks = (N_ + 127) / 128;
  int ngroups = 256;                       // k_agg grid = ngroups*8 blocks
  for (int l = 0; l < 3; ++l){
    const float* sc = (l == 0) ? nullptr : scales + (l - 1) * 128;
    const float* sh = (l == 0) ? nullptr : shifts + (l - 1) * 128;
    k_gemm<<<gemm_blocks, 512, 0, stream>>>(x, (const unsigned short*)bufA,
                                            Ws + (size_t)l * D * D, inv, sc, sh,
                                            (l == 0) ? 0 : 1, hwS, N_);
    k_agg<<<ngroups * 8, 256, 0, stream>>>(hwS, inv, offs, csrc, bs + (size_t)l * D,
                                           bufA, stats + (size_t)l * 256, N_, ngroups);
    k_bn<<<1, 128, 0, stream>>>(stats + (size_t)l * 256, gammas + (size_t)l * D,
                                betas + (size_t)l * D, scales + (size_t)l * 128,
                                shifts + (size_t)l * 128, 1.0f / (float)N_);
  }
  k_pool<<<(N_ + 255) / 256, 256, 0, stream>>>(bufA, scales + 2 * 128, shifts + 2 * 128,
                                               batch, (float*)d_out, N_);
}

// Round 11
// 557.984 us; speedup vs baseline: 1.4408x; 1.0430x over previous
//
#include <hip/hip_runtime.h>

#define D 128
#define CHUNK 512
#define NSLICE 8
#define SLW 16            // cols per slice

using short8 = __attribute__((ext_vector_type(8))) short;
using f32x4  = __attribute__((ext_vector_type(4))) float;
using f32x2  = __attribute__((ext_vector_type(2))) float;

__device__ __forceinline__ unsigned short f2bf(float f){
  unsigned u = __builtin_bit_cast(unsigned, f);
  u += 0x7fffu + ((u >> 16) & 1u);           // round-to-nearest-even
  return (unsigned short)(u >> 16);
}
__device__ __forceinline__ float bflo2f(unsigned v){
  return __builtin_bit_cast(float, v << 16);
}
__device__ __forceinline__ float bfhi2f(unsigned v){
  return __builtin_bit_cast(float, v & 0xffff0000u);
}
__device__ __forceinline__ float bfs2f(unsigned short v){
  return __builtin_bit_cast(float, ((unsigned)v) << 16);
}
// packed f32x2 -> 2xbf16 in one instruction (gfx950)
__device__ __forceinline__ unsigned cvtpk(float lo, float hi){
  unsigned r;
  asm("v_cvt_pk_bf16_f32 %0, %1, %2" : "=v"(r) : "v"(lo), "v"(hi));
  return r;
}

// ---------------- degree ----------------
__global__ void k_deg(const int* __restrict__ dst, int* __restrict__ deg, int E){
  int e = blockIdx.x * 256 + threadIdx.x;
  if (e < E) atomicAdd(&deg[dst[e]], 1);
}

// ---------------- scan (3-stage) ----------------
__global__ void k_chunksum(const int* __restrict__ deg, int* __restrict__ csum, int n){
  __shared__ int s[256];
  int tid = threadIdx.x;
  int n0 = blockIdx.x * CHUNK + tid * 2;
  int v = 0;
  if (n0     < n) v += deg[n0];
  if (n0 + 1 < n) v += deg[n0 + 1];
  s[tid] = v; __syncthreads();
  for (int off = 128; off > 0; off >>= 1){
    if (tid < off) s[tid] += s[tid + off];
    __syncthreads();
  }
  if (tid == 0) csum[blockIdx.x] = s[0];
}

__global__ void k_scanchunks(int* __restrict__ csum, int nchunks){
  __shared__ int s[256];
  int tid = threadIdx.x;
  int v = (tid < nchunks) ? csum[tid] : 0;
  s[tid] = v; __syncthreads();
  for (int off = 1; off < 256; off <<= 1){
    int t = (tid >= off) ? s[tid - off] : 0;
    __syncthreads();
    s[tid] += t;
    __syncthreads();
  }
  if (tid < nchunks) csum[tid] = s[tid] - v;   // exclusive
}

__global__ void k_offsets(const int* __restrict__ deg, const int* __restrict__ csum,
                          int* __restrict__ offs, float* __restrict__ inv, int n){
  __shared__ int s[256];
  int tid = threadIdx.x;
  int n0 = blockIdx.x * CHUNK + tid * 2;
  int d0 = (n0     < n) ? deg[n0]     : 0;
  int d1 = (n0 + 1 < n) ? deg[n0 + 1] : 0;
  int pair = d0 + d1;
  s[tid] = pair; __syncthreads();
  for (int off = 1; off < 256; off <<= 1){
    int t = (tid >= off) ? s[tid - off] : 0;
    __syncthreads();
    s[tid] += t;
    __syncthreads();
  }
  int excl = s[tid] - pair + csum[blockIdx.x];
  if (n0     <= n) offs[n0]     = excl;
  if (n0 + 1 <= n) offs[n0 + 1] = excl + d0;
  if (n0     < n) inv[n0]     = rsqrtf((float)(d0 + 1));
  if (n0 + 1 < n) inv[n0 + 1] = rsqrtf((float)(d1 + 1));
}

// ---------------- CSR fill (XCD-partitioned by dst range) ------------------
// partition p = blockIdx%8 rides round-robin dispatch -> one XCD. Each
// partition scans all edges (sequential) and keeps only dst in its range,
// so csrc lines are written by a single XCD's L2 -> stores merge, writeback
// collapses 107 MB -> ~6.4 MB.
__global__ __launch_bounds__(256)
void k_csrfill(const int* __restrict__ src, const int* __restrict__ dst,
               const int* __restrict__ offs, int* __restrict__ cursor,
               int* __restrict__ csrc, int E, int n){
  int part = blockIdx.x & 7;
  int blk  = blockIdx.x >> 3;
  int nblk = gridDim.x >> 3;
  int per = (n + 7) / 8;
  int d0 = part * per, d1 = min(d0 + per, n);
  int stride = nblk * 256;
  for (int e = blk * 256 + threadIdx.x; e < E; e += stride){
    int d = dst[e];
    if (d >= d0 && d < d1){
      int s = src[e];
      int pos = offs[d] + atomicAdd(&cursor[d], 1);
      csrc[pos] = s;
    }
  }
}

// ---------------- GEMM: hwS(bf16, slice-major) = act(hin) @ W, rows × inv --
// hwS layout: [slice][N][16] ushorts. agg input (do_norm) also slice-major.
#define WSTRIDE 136
__global__ __launch_bounds__(512)
void k_gemm(const float* __restrict__ hf, const unsigned short* __restrict__ hb,
            const float* __restrict__ W, const float* __restrict__ inv,
            const float* __restrict__ scale, const float* __restrict__ shift,
            int do_norm, unsigned short* __restrict__ hwS, int nrows){
  __shared__ unsigned short Wt[128 * WSTRIDE];  // transposed, padded
  int tid = threadIdx.x;
  for (int i = tid; i < 128 * 128; i += 512){
    int k = i >> 7, c = i & 127;
    Wt[c * WSTRIDE + k] = f2bf(W[i]);
  }
  __syncthreads();

  int wave = tid >> 6, lane = tid & 63;
  int r0 = blockIdx.x * 128 + wave * 16;
  int row = r0 + (lane & 15);
  int kg = lane >> 4;
  int rowc = row < nrows ? row : nrows - 1;

  short8 a[4];
  if (do_norm){
#pragma unroll
    for (int kt = 0; kt < 4; ++kt){
      int k0 = kt * 32 + kg * 8;                 // 8 cols within one slice
      int sl = k0 >> 4, o = k0 & 15;
      short8 raw = *(const short8*)(hb + ((long)sl * nrows + rowc) * SLW + o);
      unsigned u[4];
#pragma unroll
      for (int j = 0; j < 4; ++j){
        float lo = bfs2f((unsigned short)raw[2*j]);
        float hi = bfs2f((unsigned short)raw[2*j+1]);
        lo = fmaxf(0.f, lo * scale[k0+2*j]   + shift[k0+2*j]);
        hi = fmaxf(0.f, hi * scale[k0+2*j+1] + shift[k0+2*j+1]);
        u[j] = cvtpk(lo, hi);
      }
      a[kt] = *(short8*)u;
    }
  } else {
    const float* hrow = hf + (long)rowc * D;
#pragma unroll
    for (int kt = 0; kt < 4; ++kt){
      int k0 = kt * 32 + kg * 8;
      f32x4 v0 = *(const f32x4*)(hrow + k0);
      f32x4 v1 = *(const f32x4*)(hrow + k0 + 4);
      unsigned u[4];
      u[0] = cvtpk(v0[0], v0[1]);
      u[1] = cvtpk(v0[2], v0[3]);
      u[2] = cvtpk(v1[0], v1[1]);
      u[3] = cvtpk(v1[2], v1[3]);
      a[kt] = *(short8*)u;
    }
  }

  f32x4 acc[8] = {};
#pragma unroll
  for (int ct = 0; ct < 8; ++ct){
    int col = ct * 16 + (lane & 15);
    const unsigned short* bp = &Wt[col * WSTRIDE + kg * 8];
#pragma unroll
    for (int kt = 0; kt < 4; ++kt){
      short8 b = *(const short8*)(bp + kt * 32);
      acc[ct] = __builtin_amdgcn_mfma_f32_16x16x32_bf16(a[kt], b, acc[ct], 0, 0, 0);
    }
  }

  int colbase = lane & 15;
  int rowo = r0 + kg * 4;
  float ivr[4];
#pragma unroll
  for (int r = 0; r < 4; ++r) ivr[r] = inv[min(rowo + r, nrows - 1)];
#pragma unroll
  for (int ct = 0; ct < 8; ++ct){        // slice = ct (cols ct*16..ct*16+15)
#pragma unroll
    for (int r = 0; r < 4; ++r){
      int rr = rowo + r;
      if (rr < nrows)
        hwS[((long)ct * nrows + rr) * SLW + colbase] = f2bf(acc[ct][r] * ivr[r]);
    }
  }
}

// ---------------- aggregate + BN partial stats (sliced, node-cohort) -------
// slice g = blockIdx%8 -> one XCD (round-robin dispatch), 3.2 MB L2-resident.
// lane = node-slot(ns,8) x colpair(cp,8): 8 consecutive nodes in parallel.
// 4 edges/iter, indices prefetched one iteration ahead (4-8 VMEM in flight).
__global__ __launch_bounds__(256)
void k_agg(const unsigned short* __restrict__ hwS, const float* __restrict__ inv,
           const int* __restrict__ offs, const int* __restrict__ csrc,
           const float* __restrict__ bias,
           unsigned* __restrict__ aggS, float* __restrict__ stats, int n,
           int ngroups){
  int g   = blockIdx.x & 7;
  int grp = blockIdx.x >> 3;
  int tid = threadIdx.x, lane = tid & 63, wv = tid >> 6;
  int ns = lane >> 3;          // node slot 0..7
  int cp = lane & 7;           // col pair 0..7
  int nwaves = ngroups * 4;
  int gw = grp * 4 + wv;
  int per = (n + nwaves - 1) / nwaves;
  int n0 = min(gw * per, n), n1 = min(n0 + per, n);

  const unsigned* slice = (const unsigned*)hwS + (long)g * n * 8;  // uniform
  unsigned* oslice = aggS + (long)g * n * 8;                       // uniform

  float b0 = bias[g * 16 + cp * 2], b1 = bias[g * 16 + cp * 2 + 1];
  float s0 = 0, s1 = 0, q0 = 0, q1 = 0;

  for (int base = n0; base < n1; base += 8){
    int node = base + ns;
    bool act = node < n1;
    int ndc = act ? node : n1 - 1;
    int e  = offs[ndc];
    int ee = offs[ndc + 1];
    float a0 = 0, a1 = 0;

    int i0 = csrc[(e     < ee) ? e     : 0];
    int i1 = csrc[(e + 1 < ee) ? e + 1 : 0];
    int i2 = csrc[(e + 2 < ee) ? e + 2 : 0];
    int i3 = csrc[(e + 3 < ee) ? e + 3 : 0];
    while (__any(e < ee)){
      // prefetch next iteration's indices (independent of this iter's gathers)
      int j0 = csrc[(e + 4 < ee) ? e + 4 : 0];
      int j1 = csrc[(e + 5 < ee) ? e + 5 : 0];
      int j2 = csrc[(e + 6 < ee) ? e + 6 : 0];
      int j3 = csrc[(e + 7 < ee) ? e + 7 : 0];
      unsigned v0 = slice[i0 * 8 + cp];
      unsigned v1 = slice[i1 * 8 + cp];
      unsigned v2 = slice[i2 * 8 + cp];
      unsigned v3 = slice[i3 * 8 + cp];
      v0 = (e     < ee) ? v0 : 0u;
      v1 = (e + 1 < ee) ? v1 : 0u;
      v2 = (e + 2 < ee) ? v2 : 0u;
      v3 = (e + 3 < ee) ? v3 : 0u;
      a0 += (bflo2f(v0) + bflo2f(v1)) + (bflo2f(v2) + bflo2f(v3));
      a1 += (bfhi2f(v0) + bfhi2f(v1)) + (bfhi2f(v2) + bfhi2f(v3));
      i0 = j0; i1 = j1; i2 = j2; i3 = j3;
      e += 4;
    }

    if (act){
      unsigned selfv = slice[node * 8 + cp];
      float ivd = inv[node];
      a0 = (a0 + bflo2f(selfv)) * ivd + b0;
      a1 = (a1 + bfhi2f(selfv)) * ivd + b1;
      unsigned pk = ((unsigned)f2bf(a1) << 16) | (unsigned)f2bf(a0);
      __builtin_nontemporal_store(pk, oslice + node * 8 + cp);
      s0 += a0; s1 += a1; q0 += a0 * a0; q1 += a1 * a1;
    }
  }

  // fold the 8 node slots (lane bits 3..5) once per kernel
  s0 += __shfl_xor(s0, 8, 64);  s1 += __shfl_xor(s1, 8, 64);
  q0 += __shfl_xor(q0, 8, 64);  q1 += __shfl_xor(q1, 8, 64);
  s0 += __shfl_xor(s0, 16, 64); s1 += __shfl_xor(s1, 16, 64);
  q0 += __shfl_xor(q0, 16, 64); q1 += __shfl_xor(q1, 16, 64);
  s0 += __shfl_xor(s0, 32, 64); s1 += __shfl_xor(s1, 32, 64);
  q0 += __shfl_xor(q0, 32, 64); q1 += __shfl_xor(q1, 32, 64);

  __shared__ float red[4][8][4];
  if (ns == 0){
    red[wv][cp][0] = s0; red[wv][cp][1] = s1;
    red[wv][cp][2] = q0; red[wv][cp][3] = q1;
  }
  __syncthreads();
  if (tid < 8){
    float t0 = 0, t1 = 0, t2 = 0, t3 = 0;
#pragma unroll
    for (int w = 0; w < 4; ++w){
      t0 += red[w][tid][0]; t1 += red[w][tid][1];
      t2 += red[w][tid][2]; t3 += red[w][tid][3];
    }
    int c = g * 16 + tid * 2;
    atomicAdd(&stats[c],           t0);
    atomicAdd(&stats[c + 1],       t1);
    atomicAdd(&stats[128 + c],     t2);
    atomicAdd(&stats[128 + c + 1], t3);
  }
}

// ---------------- BN finalize ----------------
__global__ void k_bn(const float* __restrict__ stats, const float* __restrict__ gamma,
                     const float* __restrict__ beta, float* __restrict__ scale,
                     float* __restrict__ shift, float invn){
  int c = threadIdx.x;
  float mean = stats[c] * invn;
  float var = stats[128 + c] * invn - mean * mean;
  float isd = rsqrtf(var + 1e-5f);
  float sc = gamma[c] * isd;
  scale[c] = sc;
  shift[c] = beta[c] - mean * sc;
}

// ---------------- pool (fused BN+ReLU of last layer, sliced bf16 agg) ------
__global__ __launch_bounds__(256)
void k_pool(const unsigned* __restrict__ aggS, const float* __restrict__ scale,
            const float* __restrict__ shift, const int* __restrict__ batch,
            float* __restrict__ out, int n){
  int tid = threadIdx.x, lane = tid & 63, wv = tid >> 6;
  int gw = blockIdx.x * 4 + wv;
  int n0 = gw * 64;
  if (n0 >= n) return;
  int n1 = min(n0 + 64, n);
  int c0 = lane * 2;
  int sl = lane >> 3, cp = lane & 7;
  long sbase = (long)sl * n * 8;
  float sc0 = scale[c0], sc1 = scale[c0 + 1];
  float sh0 = shift[c0], sh1 = shift[c0 + 1];
  int g = batch[n0];
  float a0 = 0, a1 = 0;
  for (int nd = n0; nd < n1; ++nd){
    int gn = batch[nd];
    if (gn != g){
      atomicAdd(&out[(long)g * D + c0],     a0);
      atomicAdd(&out[(long)g * D + c0 + 1], a1);
      a0 = 0; a1 = 0; g = gn;
    }
    unsigned v = aggS[sbase + (long)nd * 8 + cp];
    a0 += fmaxf(0.f, bflo2f(v) * sc0 + sh0);
    a1 += fmaxf(0.f, bfhi2f(v) * sc1 + sh1);
  }
  atomicAdd(&out[(long)g * D + c0],     a0);
  atomicAdd(&out[(long)g * D + c0 + 1], a1);
}

extern "C" void kernel_launch(void* const* d_in, const int* in_sizes, int n_in,
                              void* d_out, int out_size, void* d_ws, size_t ws_size,
                              hipStream_t stream){
  const float* x      = (const float*)d_in[0];
  const int*   ei     = (const int*)d_in[1];
  const int*   batch  = (const int*)d_in[2];
  const float* Ws     = (const float*)d_in[3];
  const float* bs     = (const float*)d_in[4];
  const float* gammas = (const float*)d_in[5];
  const float* betas  = (const float*)d_in[6];

  const int E_ = in_sizes[1] / 2;
  const int N_ = in_sizes[2];
  const int* src = ei;
  const int* dst = ei + E_;

  char* p = (char*)d_ws;
  auto alloc = [&](size_t bytes) -> void* {
    void* r = (void*)p;
    p += (bytes + 255) & ~(size_t)255;
    return r;
  };
  unsigned*       bufA   = (unsigned*)      alloc((size_t)N_ * D * 2);   // bf16 agg, sliced
  unsigned short* hwS    = (unsigned short*)alloc((size_t)N_ * D * 2);   // bf16 hw, sliced
  int*            deg    = (int*)           alloc((size_t)N_ * 4);
  float*          inv    = (float*)         alloc((size_t)N_ * 4);
  int*            offs   = (int*)           alloc((size_t)(N_ + 1) * 4);
  int*            cursor = (int*)           alloc((size_t)N_ * 4);
  int*            csrc   = (int*)           alloc((size_t)E_ * 4);
  float*          stats  = (float*)         alloc(3 * 256 * 4);
  float*          scales = (float*)         alloc(3 * 128 * 4);
  float*          shifts = (float*)         alloc(3 * 128 * 4);
  int*            csum   = (int*)           alloc(256 * 4);

  hipMemsetAsync(deg,    0, (size_t)N_ * 4, stream);
  hipMemsetAsync(cursor, 0, (size_t)N_ * 4, stream);
  hipMemsetAsync(stats,  0, 3 * 256 * 4, stream);
  hipMemsetAsync(d_out,  0, (size_t)out_size * 4, stream);

  int nchunks = (N_ + CHUNK - 1) / CHUNK;
  k_deg       <<<(E_ + 255) / 256, 256, 0, stream>>>(dst, deg, E_);
  k_chunksum  <<<nchunks, 256, 0, stream>>>(deg, csum, N_);
  k_scanchunks<<<1, 256, 0, stream>>>(csum, nchunks);
  k_offsets   <<<nchunks, 256, 0, stream>>>(deg, csum, offs, inv, N_);
  k_csrfill   <<<2048, 256, 0, stream>>>(src, dst, offs, cursor, csrc, E_, N_);

  int gemm_blocks = (N_ + 127) / 128;
  int ngroups = 256;                       // k_agg grid = ngroups*8 blocks
  for (int l = 0; l < 3; ++l){
    const float* sc = (l == 0) ? nullptr : scales + (l - 1) * 128;
    const float* sh = (l == 0) ? nullptr : shifts + (l - 1) * 128;
    k_gemm<<<gemm_blocks, 512, 0, stream>>>(x, (const unsigned short*)bufA,
                                            Ws + (size_t)l * D * D, inv, sc, sh,
                                            (l == 0) ? 0 : 1, hwS, N_);
    k_agg<<<ngroups * 8, 256, 0, stream>>>(hwS, inv, offs, csrc, bs + (size_t)l * D,
                                           bufA, stats + (size_t)l * 256, N_, ngroups);
    k_bn<<<1, 128, 0, stream>>>(stats + (size_t)l * 256, gammas + (size_t)l * D,
                                betas + (size_t)l * D, scales + (size_t)l * 128,
                                shifts + (size_t)l * 128, 1.0f / (float)N_);
  }
  k_pool<<<(N_ + 255) / 256, 256, 0, stream>>>(bufA, scales + 2 * 128, shifts + 2 * 128,
                                               batch, (float*)d_out, N_);
}